// Round 2
// baseline (349.545 us; speedup 1.0000x reference)
//
#include <hip/hip_runtime.h>

typedef float v2f __attribute__((ext_vector_type(2)));

#define KH 5
#define KW 5
#define HH 256
#define WW 256
#define HO 252
#define WO 252
#define NB 16
#define NO 64
#define PLANE (HO * WO)
#define NPASS 5
#define XC 85                    // 84 cols used + 1 pad (bank spread)

// Output plane stride = 63504 floats == 16 (mod 32): even-o planes have 128B
// lines at l == 4k (mod 32), odd-o planes shifted by 16 floats. Each block
// owns even-o l in [Le, Le+64) and odd-o l in [Le-16, Le+48), produced by 5
// sixteen-wide passes (pass 0: store odd only, 1-3: both, 4: even only).
// Consecutive passes complete each 128B line inside ONE block -> full-line
// L2 writebacks instead of cross-XCD half-line RMW.
// Thread map per pass: p = t&15 (l offset), b = (t>>4)&15, og = t>>8.
__global__ __launch_bounds__(512, 4)
void rbf_conv2d_kernel(const float* __restrict__ x, const float* __restrict__ w,
                       float* __restrict__ out) {
    __shared__ float xs[NB][KH][XC];      // 27200 B
    __shared__ float wn[NO];
    __shared__ float pS1[2][8][16];       // double-buffered partial sums
    __shared__ float pS2[2][8][16];

    const int t  = threadIdx.x;
    const int k  = blockIdx.y;
    const int a0 = (4 * k) & 31;                       // even-o line phase
    const int Le = a0 - 64 + 64 * (int)blockIdx.x;
    if (Le - 16 >= WO || Le + 64 <= 0) return;         // uniform, pre-barrier
    const int colbase = Le - 16;                        // x-col of window col 0

    // ---- stage x window (cols clamped; clamped cols only feed masked lanes) ----
    for (int idx = t; idx < NB * KH * XC; idx += 512) {
        int b   = idx / (KH * XC);
        int rem = idx - b * (KH * XC);
        int r   = rem / XC;
        int c   = rem - r * XC;
        int col = colbase + c;
        col = col < 0 ? 0 : (col > WW - 1 ? WW - 1 : col);
        xs[b][r][c] = x[(b * HH + k + r) * WW + col];
    }
    if (t < NO) {
        float s = 0.f;
        #pragma unroll
        for (int i = 0; i < 25; ++i) { float v = w[t * 25 + i]; s = fmaf(v, v, s); }
        wn[t] = s;
    }
    __syncthreads();

    const int p     = t & 15;
    const int b     = (t >> 4) & 15;
    const int obase = __builtin_amdgcn_readfirstlane((t >> 8) << 5);
    const int wv    = t >> 6;
    const int lane  = t & 63;
    const int bo_base = ((b * NO + obase) * HO + k) * WO;

    #pragma unroll 1
    for (int pi = 0; pi < NPASS; ++pi) {
        const int  Lp     = colbase + 16 * pi;          // this pass's l-origin
        const bool active = (Lp + 16 > 0) && (Lp < WO); // block-uniform
        const int  pb     = pi & 1;

        v2f   dv[16];
        float s1 = 0.f, s2 = 0.f;

        if (active) {
            // ---- patch into registers, packed as v2f pairs ----
            float pr[25];
            float pn = 0.f;
            #pragma unroll
            for (int r = 0; r < KH; ++r)
                #pragma unroll
                for (int c = 0; c < KW; ++c) {
                    float v = xs[b][r][16 * pi + p + c];
                    pr[r * KW + c] = v;
                    pn = fmaf(v, v, pn);
                }
            v2f prv[12];
            #pragma unroll
            for (int i = 0; i < 12; ++i) { prv[i].x = pr[2 * i]; prv[i].y = pr[2 * i + 1]; }
            const float pr24 = pr[24];

            // ---- 32 distances + fused sum / sum-of-squares ----
            #pragma unroll
            for (int j = 0; j < 16; ++j) {
                float cr0, cr1;
                {
                    const float* __restrict__ wr = w + (obase + 2 * j) * 25;
                    v2f acc = {0.f, 0.f};
                    #pragma unroll
                    for (int i = 0; i < 12; ++i) {
                        v2f wv_; wv_.x = wr[2 * i]; wv_.y = wr[2 * i + 1];
                        acc = __builtin_elementwise_fma(prv[i], wv_, acc);
                    }
                    cr0 = acc.x + acc.y + pr24 * wr[24];
                }
                {
                    const float* __restrict__ wr = w + (obase + 2 * j + 1) * 25;
                    v2f acc = {0.f, 0.f};
                    #pragma unroll
                    for (int i = 0; i < 12; ++i) {
                        v2f wv_; wv_.x = wr[2 * i]; wv_.y = wr[2 * i + 1];
                        acc = __builtin_elementwise_fma(prv[i], wv_, acc);
                    }
                    cr1 = acc.x + acc.y + pr24 * wr[24];
                }
                float d20 = fmaxf(fmaf(-2.f, cr0, pn + wn[obase + 2 * j]),     1e-12f);
                float d21 = fmaxf(fmaf(-2.f, cr1, pn + wn[obase + 2 * j + 1]), 1e-12f);
                s2 += d20 + d21;
                dv[j].x = __builtin_amdgcn_sqrtf(d20);
                dv[j].y = __builtin_amdgcn_sqrtf(d21);
                s1 += dv[j].x + dv[j].y;
            }

            // ---- wave reduce over the 4 b-lanes sharing p ----
            s1 += __shfl_xor(s1, 16); s2 += __shfl_xor(s2, 16);
            s1 += __shfl_xor(s1, 32); s2 += __shfl_xor(s2, 32);
            if (lane < 16) { pS1[pb][wv][lane] = s1; pS2[pb][wv][lane] = s2; }
        }
        __syncthreads();   // uniform: every wave, every pass

        if (active) {
            float S1 = 0.f, S2 = 0.f;
            #pragma unroll
            for (int q = 0; q < 8; ++q) { S1 += pS1[pb][q][p]; S2 += pS2[pb][q][p]; }
            // sample var over 1024 dists: (sum d^2 - (sum d)^2/N) / (N-1)
            const float var  = (S2 - S1 * S1 * (1.0f / 1024.0f)) * (1.0f / 1023.0f);
            const float cinv = -0.72134752044448170368f / var;   // -0.5*log2(e)/var

            const int  l   = Lp + p;
            const bool ok  = (l >= 0) && (l < WO);
            const bool okE = ok && (pi >= 1);            // even-o stored passes 1..4
            const bool okO = ok && (pi <= 3);            // odd-o  stored passes 0..3
            v2f cv; cv.x = cinv; cv.y = cinv;
            const int base = bo_base + l;
            #pragma unroll
            for (int j = 0; j < 16; ++j) {
                v2f tt = dv[j] * dv[j];
                tt = tt * cv;
                float e0 = exp2f(tt.x);
                float e1 = exp2f(tt.y);
                if (okE) out[base + (2 * j) * PLANE]     = e0;
                if (okO) out[base + (2 * j + 1) * PLANE] = e1;
            }
        }
        // no trailing barrier needed: partial buffers are double-buffered by
        // pass parity; earliest rewrite of pS[pb] is two passes (one barrier) away
    }
}

extern "C" void kernel_launch(void* const* d_in, const int* in_sizes, int n_in,
                              void* d_out, int out_size, void* d_ws, size_t ws_size,
                              hipStream_t stream) {
    const float* x = (const float*)d_in[0];
    const float* w = (const float*)d_in[1];
    float* out = (float*)d_out;
    dim3 grid(6, HO);   // 6 64-wide dual-parity windows x 252 rows
    rbf_conv2d_kernel<<<grid, 512, 0, stream>>>(x, w, out);
}

// Round 3
// 340.243 us; speedup vs baseline: 1.0273x; 1.0273x over previous
//
#include <hip/hip_runtime.h>

typedef float v2f __attribute__((ext_vector_type(2)));

#define KH 5
#define KW 5
#define HH 256
#define WW 256
#define HO 252
#define WO 252
#define NB 16
#define NO 64
#define PLANE (HO * WO)
#define TLW 64
#define XCOLS (TLW + KW - 1)   // 68

// 64-wide l-tiles: one wave spans 64 consecutive l, so every store instruction
// is a single 256B contiguous, 64B-aligned run in one output plane (the
// a=(4k)&15 shift keeps 12k+l0 == 0 mod 16). This replaces the old 64B-per-
// plane-hop store stream (DRAM row-activate bound, ~1.8 TB/s effective) with
// 4x longer runs. 128 outputs/thread don't fit in registers, so two-phase
// recompute: A) d^2 -> fused sum d / sum d^2 stats, B) recompute d^2 ->
// exp2(d^2 * cinv) -> store (no sqrt on store path).
// Thread map: lane = t&63 (l offset), bg = t>>6 (wave id, SGPR) -> b in
// {bg, bg+8}; o loop 0..63 is wave-uniform -> weights via s_load.
__global__ __launch_bounds__(512, 4)
void rbf_conv2d_kernel(const float* __restrict__ x, const float* __restrict__ w,
                       float* __restrict__ out) {
    __shared__ float xs[NB][KH][XCOLS];   // 21760 B
    __shared__ float wn[NO];
    __shared__ float pS1[8][TLW];
    __shared__ float pS2[8][TLW];
    __shared__ float cinv_s[TLW];

    const int t = threadIdx.x;
    const int k = blockIdx.y;
    const int a = (4 * k) & 15;
    const int l0 = a - TLW + TLW * (int)blockIdx.x;
    if (l0 >= WO || l0 + TLW <= 0) return;      // uniform, pre-barrier

    // ---- stage x window (cols clamped; clamped cols only feed masked lanes) ----
    for (int idx = t; idx < NB * KH * XCOLS; idx += 512) {
        int b   = idx / (KH * XCOLS);
        int rem = idx - b * (KH * XCOLS);
        int r   = rem / XCOLS;
        int c   = rem - r * XCOLS;
        int col = l0 + c;
        col = col < 0 ? 0 : (col > WW - 1 ? WW - 1 : col);
        xs[b][r][c] = x[(b * HH + k + r) * WW + col];
    }
    if (t < NO) {
        float s = 0.f;
        #pragma unroll
        for (int i = 0; i < 25; ++i) { float v = w[t * 25 + i]; s = fmaf(v, v, s); }
        wn[t] = s;
    }
    __syncthreads();

    const int lane = t & 63;
    const int bg   = __builtin_amdgcn_readfirstlane(t >> 6);
    const int l    = l0 + lane;

    // ================= phase A: stats =================
    float s1 = 0.f, s2 = 0.f;
    #pragma unroll 1
    for (int bi = 0; bi < 2; ++bi) {
        const int b = bg + 8 * bi;
        float pr[25];
        float pn = 0.f;
        #pragma unroll
        for (int r = 0; r < KH; ++r)
            #pragma unroll
            for (int c = 0; c < KW; ++c) {
                float v = xs[b][r][lane + c];     // wave-uniform b,r,c -> conflict-free
                pr[r * KW + c] = v;
                pn = fmaf(v, v, pn);
            }
        v2f prv[12];
        #pragma unroll
        for (int i = 0; i < 12; ++i) { prv[i].x = pr[2 * i]; prv[i].y = pr[2 * i + 1]; }
        const float pr24 = pr[24];

        #pragma unroll 8
        for (int j = 0; j < 32; ++j) {
            float cr0, cr1;
            {
                const float* __restrict__ wr = w + (2 * j) * 25;      // uniform -> s_load
                v2f acc = {0.f, 0.f};
                #pragma unroll
                for (int i = 0; i < 12; ++i) {
                    v2f wv_; wv_.x = wr[2 * i]; wv_.y = wr[2 * i + 1];
                    acc = __builtin_elementwise_fma(prv[i], wv_, acc);
                }
                cr0 = acc.x + acc.y + pr24 * wr[24];
            }
            {
                const float* __restrict__ wr = w + (2 * j + 1) * 25;
                v2f acc = {0.f, 0.f};
                #pragma unroll
                for (int i = 0; i < 12; ++i) {
                    v2f wv_; wv_.x = wr[2 * i]; wv_.y = wr[2 * i + 1];
                    acc = __builtin_elementwise_fma(prv[i], wv_, acc);
                }
                cr1 = acc.x + acc.y + pr24 * wr[24];
            }
            v2f wn2 = *(const v2f*)&wn[2 * j];                        // one ds_read_b64
            float d20 = fmaxf(fmaf(-2.f, cr0, pn + wn2.x), 1e-12f);
            float d21 = fmaxf(fmaf(-2.f, cr1, pn + wn2.y), 1e-12f);
            s2 += d20 + d21;
            s1 += __builtin_amdgcn_sqrtf(d20) + __builtin_amdgcn_sqrtf(d21);
        }
    }
    pS1[bg][lane] = s1;
    pS2[bg][lane] = s2;
    __syncthreads();

    if (t < TLW) {
        float S1 = 0.f, S2 = 0.f;
        #pragma unroll
        for (int q = 0; q < 8; ++q) { S1 += pS1[q][t]; S2 += pS2[q][t]; }
        // sample var over 1024 dists: (sum d^2 - (sum d)^2/N) / (N-1)
        const float var = (S2 - S1 * S1 * (1.0f / 1024.0f)) * (1.0f / 1023.0f);
        cinv_s[t] = -0.72134752044448170368f / var;   // -0.5*log2(e)/var
    }
    __syncthreads();

    // ================= phase B: recompute + store =================
    const float ci  = cinv_s[lane];
    const bool  ok  = ((unsigned)l < (unsigned)WO);
    #pragma unroll 1
    for (int bi = 0; bi < 2; ++bi) {
        const int b = bg + 8 * bi;
        float pr[25];
        float pn = 0.f;
        #pragma unroll
        for (int r = 0; r < KH; ++r)
            #pragma unroll
            for (int c = 0; c < KW; ++c) {
                float v = xs[b][r][lane + c];
                pr[r * KW + c] = v;
                pn = fmaf(v, v, pn);
            }
        v2f prv[12];
        #pragma unroll
        for (int i = 0; i < 12; ++i) { prv[i].x = pr[2 * i]; prv[i].y = pr[2 * i + 1]; }
        const float pr24 = pr[24];

        const int base_b = (b * NO) * PLANE + k * WO + l;
        #pragma unroll 8
        for (int j = 0; j < 32; ++j) {
            float cr0, cr1;
            {
                const float* __restrict__ wr = w + (2 * j) * 25;
                v2f acc = {0.f, 0.f};
                #pragma unroll
                for (int i = 0; i < 12; ++i) {
                    v2f wv_; wv_.x = wr[2 * i]; wv_.y = wr[2 * i + 1];
                    acc = __builtin_elementwise_fma(prv[i], wv_, acc);
                }
                cr0 = acc.x + acc.y + pr24 * wr[24];
            }
            {
                const float* __restrict__ wr = w + (2 * j + 1) * 25;
                v2f acc = {0.f, 0.f};
                #pragma unroll
                for (int i = 0; i < 12; ++i) {
                    v2f wv_; wv_.x = wr[2 * i]; wv_.y = wr[2 * i + 1];
                    acc = __builtin_elementwise_fma(prv[i], wv_, acc);
                }
                cr1 = acc.x + acc.y + pr24 * wr[24];
            }
            v2f wn2 = *(const v2f*)&wn[2 * j];
            float d20 = fmaxf(fmaf(-2.f, cr0, pn + wn2.x), 1e-12f);
            float d21 = fmaxf(fmaf(-2.f, cr1, pn + wn2.y), 1e-12f);
            // exp(-0.5 d^2/var) = exp2(d^2 * cinv); d^2 used directly, no sqrt
            float e0 = exp2f(d20 * ci);
            float e1 = exp2f(d21 * ci);
            if (ok) {
                out[base_b + (2 * j) * PLANE]     = e0;   // 64 lanes = 256B run
                out[base_b + (2 * j + 1) * PLANE] = e1;
            }
        }
    }
}

extern "C" void kernel_launch(void* const* d_in, const int* in_sizes, int n_in,
                              void* d_out, int out_size, void* d_ws, size_t ws_size,
                              hipStream_t stream) {
    const float* x = (const float*)d_in[0];
    const float* w = (const float*)d_in[1];
    float* out = (float*)d_out;
    dim3 grid(5, HO);   // 5 shifted 64-wide tiles x 252 rows
    rbf_conv2d_kernel<<<grid, 512, 0, stream>>>(x, w, out);
}

// Round 5
// 333.235 us; speedup vs baseline: 1.0489x; 1.0210x over previous
//
#include <hip/hip_runtime.h>

typedef float v2f __attribute__((ext_vector_type(2)));
typedef float v4f __attribute__((ext_vector_type(4)));

#define KH 5
#define KW 5
#define HH 256
#define WW 256
#define HO 252
#define WO 252
#define NB 16
#define NO 64
#define PLANE (HO * WO)

// ---- workspace layout (d_ws): cinv[63616] then pn[16*63504 + 64] ----
#define CINV_FLOATS 63616            // 252*252 rounded up + slack for x4 overreads
#define PN_FLOATS   (NB * PLANE + 64)

// ================= pass 1: per-pixel stats -> cinv, pn =================
// Grid (4, 252): 64-wide l tiles. Computes d over all 16b x 64o per pixel,
// fused sum/sum-of-squares, writes cinv = -0.5*log2e/var (254 KB) and the
// patch norms pn[b][k][l] (4 MB) so pass 2 only recomputes the cross term.
#define T1W 64
#define XC1 69                        // 68 cols + 1 pad

__global__ __launch_bounds__(512, 4)
void rbf_stats_kernel(const float* __restrict__ x, const float* __restrict__ w,
                      float* __restrict__ cinvb, float* __restrict__ pnb) {
    __shared__ float xs[NB][KH][XC1];
    __shared__ float wn[NO];
    __shared__ float pS1[8][T1W];
    __shared__ float pS2[8][T1W];

    const int t  = threadIdx.x;
    const int k  = blockIdx.y;
    const int l0 = (int)blockIdx.x * T1W;

    for (int idx = t; idx < NB * KH * 68; idx += 512) {
        int b   = idx / (KH * 68);
        int rem = idx - b * (KH * 68);
        int r   = rem / 68;
        int c   = rem - r * 68;
        int col = l0 + c;
        col = col > WW - 1 ? WW - 1 : col;     // clamp only feeds invalid lanes
        xs[b][r][c] = x[(b * HH + k + r) * WW + col];
    }
    if (t < NO) {
        float s = 0.f;
        #pragma unroll
        for (int i = 0; i < 25; ++i) { float v = w[t * 25 + i]; s = fmaf(v, v, s); }
        wn[t] = s;
    }
    __syncthreads();

    const int lane = t & 63;
    const int bg   = __builtin_amdgcn_readfirstlane(t >> 6);
    const int l    = l0 + lane;

    float s1 = 0.f, s2 = 0.f;
    #pragma unroll 1
    for (int bi = 0; bi < 2; ++bi) {
        const int b = bg + 8 * bi;
        float pr[25];
        float pn = 0.f;
        #pragma unroll
        for (int r = 0; r < KH; ++r)
            #pragma unroll
            for (int c = 0; c < KW; ++c) {
                float v = xs[b][r][lane + c];
                pr[r * KW + c] = v;
                pn = fmaf(v, v, pn);
            }
        if (l < WO) pnb[b * PLANE + k * WO + l] = pn;   // 4 MB table for pass 2

        v2f prv[12];
        #pragma unroll
        for (int i = 0; i < 12; ++i) { prv[i].x = pr[2 * i]; prv[i].y = pr[2 * i + 1]; }
        const float pr24 = pr[24];

        #pragma unroll 8
        for (int j = 0; j < 32; ++j) {
            float cr0, cr1;
            {
                const float* __restrict__ wr = w + (2 * j) * 25;      // uniform -> s_load
                v2f acc = {0.f, 0.f};
                #pragma unroll
                for (int i = 0; i < 12; ++i) {
                    v2f wv_; wv_.x = wr[2 * i]; wv_.y = wr[2 * i + 1];
                    acc = __builtin_elementwise_fma(prv[i], wv_, acc);
                }
                cr0 = acc.x + acc.y + pr24 * wr[24];
            }
            {
                const float* __restrict__ wr = w + (2 * j + 1) * 25;
                v2f acc = {0.f, 0.f};
                #pragma unroll
                for (int i = 0; i < 12; ++i) {
                    v2f wv_; wv_.x = wr[2 * i]; wv_.y = wr[2 * i + 1];
                    acc = __builtin_elementwise_fma(prv[i], wv_, acc);
                }
                cr1 = acc.x + acc.y + pr24 * wr[24];
            }
            v2f wn2 = *(const v2f*)&wn[2 * j];
            float d20 = fmaxf(fmaf(-2.f, cr0, pn + wn2.x), 1e-12f);
            float d21 = fmaxf(fmaf(-2.f, cr1, pn + wn2.y), 1e-12f);
            s2 += d20 + d21;
            s1 += __builtin_amdgcn_sqrtf(d20) + __builtin_amdgcn_sqrtf(d21);
        }
    }
    pS1[bg][lane] = s1;
    pS2[bg][lane] = s2;
    __syncthreads();

    if (t < T1W) {
        float S1 = 0.f, S2 = 0.f;
        #pragma unroll
        for (int q = 0; q < 8; ++q) { S1 += pS1[q][t]; S2 += pS2[q][t]; }
        const float var = (S2 - S1 * S1 * (1.0f / 1024.0f)) * (1.0f / 1023.0f);
        const int ll = l0 + t;
        if (ll < WO) cinvb[k * WO + ll] = -0.72134752044448170368f / var;
    }
}

// ================= pass 2: per-(b,o)-plane contiguous writes =================
// Grid (6, 64, 16): block = one (b,o) plane x 42-row chunk -> its entire write
// region is one contiguous 169 KB span (fill-like HBM writeback stream).
// Recomputes only cross (25 FMA/px) from a 48 KB LDS x-slab; pn/cinv from L2.
#define RCH 42
#define XR  46
#define XW  264                       // 256 + 8 zero pad (tail windows)

__global__ __launch_bounds__(512, 4)
void rbf_out_kernel(const float* __restrict__ x, const float* __restrict__ w,
                    const float* __restrict__ cinvb, const float* __restrict__ pnb,
                    float* __restrict__ out) {
    __shared__ float xs[XR][XW];      // 48,576 B -> 3 blocks/CU by LDS

    const int t  = threadIdx.x;
    const int k0 = (int)blockIdx.x * RCH;
    const int o  = blockIdx.y;
    const int b  = blockIdx.z;

    for (int idx = t; idx < XR * 64; idx += 512) {
        const int row = idx >> 6, c4 = (idx & 63) << 2;
        *(v4f*)&xs[row][c4] = *(const v4f*)&x[(b * HH + k0 + row) * WW + c4];
    }
    if (t < XR * 2) {                 // zero the 8-col pad
        const int row = t >> 1, c = 256 + ((t & 1) << 2);
        v4f z = {0.f, 0.f, 0.f, 0.f};
        *(v4f*)&xs[row][c] = z;
    }
    const float* __restrict__ wp = w + o * 25;   // uniform -> scalar loads
    float ws[25]; float wnv = 0.f;
    #pragma unroll
    for (int i = 0; i < 25; ++i) { ws[i] = wp[i]; wnv = fmaf(ws[i], ws[i], wnv); }
    __syncthreads();

    const int ct = t & 31;            // col octet: l = 8*ct .. 8*ct+7
    const int rs = t >> 5;            // row stream 0..15
    const int c0 = ct << 3;
    const int obase = (b * NO + o) * PLANE;

    #pragma unroll 1
    for (int it = 0; it < 3; ++it) {
        const int ki = it * 16 + rs;
        if (ki >= RCH) continue;      // exec-masked tail (no barrier inside loop)
        const int gk = k0 + ki;

        float cr[8] = {0.f, 0.f, 0.f, 0.f, 0.f, 0.f, 0.f, 0.f};
        #pragma unroll
        for (int r = 0; r < KH; ++r) {
            const float* rowp = &xs[ki + r][c0];
            v4f va = *(const v4f*)rowp;
            v4f vb = *(const v4f*)(rowp + 4);
            v4f vc = *(const v4f*)(rowp + 8);
            float v[12] = {va.x, va.y, va.z, va.w, vb.x, vb.y, vb.z, vb.w,
                           vc.x, vc.y, vc.z, vc.w};
            #pragma unroll
            for (int j = 0; j < 8; ++j)
                #pragma unroll
                for (int c = 0; c < KW; ++c)
                    cr[j] = fmaf(v[j + c], ws[r * KW + c], cr[j]);
        }

        const int px = gk * WO + c0;
        v4f pA = *(const v4f*)&pnb[b * PLANE + px];
        v4f pB = *(const v4f*)&pnb[b * PLANE + px + 4];
        v4f cA = *(const v4f*)&cinvb[px];
        v4f cB = *(const v4f*)&cinvb[px + 4];

        v4f oA, oB;
        oA.x = exp2f(fmaxf(fmaf(-2.f, cr[0], pA.x + wnv), 1e-12f) * cA.x);
        oA.y = exp2f(fmaxf(fmaf(-2.f, cr[1], pA.y + wnv), 1e-12f) * cA.y);
        oA.z = exp2f(fmaxf(fmaf(-2.f, cr[2], pA.z + wnv), 1e-12f) * cA.z);
        oA.w = exp2f(fmaxf(fmaf(-2.f, cr[3], pA.w + wnv), 1e-12f) * cA.w);
        oB.x = exp2f(fmaxf(fmaf(-2.f, cr[4], pB.x + wnv), 1e-12f) * cB.x);
        oB.y = exp2f(fmaxf(fmaf(-2.f, cr[5], pB.y + wnv), 1e-12f) * cB.y);
        oB.z = exp2f(fmaxf(fmaf(-2.f, cr[6], pB.z + wnv), 1e-12f) * cB.z);
        oB.w = exp2f(fmaxf(fmaf(-2.f, cr[7], pB.w + wnv), 1e-12f) * cB.w);

        *(v4f*)&out[obase + px] = oA;             // l 8ct..8ct+3 always valid
        if (ct < 31) *(v4f*)&out[obase + px + 4] = oB;   // skip l>=252 tail
    }
}

extern "C" void kernel_launch(void* const* d_in, const int* in_sizes, int n_in,
                              void* d_out, int out_size, void* d_ws, size_t ws_size,
                              hipStream_t stream) {
    const float* x = (const float*)d_in[0];
    const float* w = (const float*)d_in[1];
    float* out  = (float*)d_out;
    float* cinv = (float*)d_ws;
    float* pnb  = (float*)d_ws + CINV_FLOATS;

    dim3 g1(4, HO);
    rbf_stats_kernel<<<g1, 512, 0, stream>>>(x, w, cinv, pnb);
    dim3 g2(6, NO, NB);
    rbf_out_kernel<<<g2, 512, 0, stream>>>(x, w, cinv, pnb, out);
}